// Round 1
// baseline (29.534 us; speedup 1.0000x reference)
//
#include <hip/hip_runtime.h>

// target = latent @ W + b  (row-wise GEMV, D=1024 -> 3)
// out    = P*noise + (1-P)*target,  P = prod_{t=1..steps} t/steps
// (closed form of the affine scan; P ~ 3e-21 for steps=50)

constexpr int D = 1024;

__global__ __launch_bounds__(256) void diff_init_kernel(
    const float* __restrict__ latent,   // [rows][1024]
    const float* __restrict__ W,        // [1024][3]
    const float* __restrict__ bvec,     // [3]
    const float* __restrict__ noise,    // [rows][3]
    const int*   __restrict__ steps_p,  // scalar
    float*       __restrict__ out,      // [rows][3]
    int rows)
{
    const int lane   = threadIdx.x & 63;
    const int wave   = blockIdx.x * (blockDim.x >> 6) + (threadIdx.x >> 6);
    const int nwaves = gridDim.x * (blockDim.x >> 6);

    // sequential product of alphas, same order as the reference scan
    const int steps = steps_p[0];
    float P = 1.0f;
    for (int t = steps; t >= 1; --t) P *= (float)t / (float)steps;
    const float Q = 1.0f - P;

    // Per-lane W fragment: lane covers d in [(it*64+lane)*4, +4) for it=0..3.
    // W rows are 3 floats, so 4 consecutive d's = 12 consecutive floats,
    // base byte offset = idx*48 -> always 16B-aligned -> three float4 loads.
    float w[4][12];
    #pragma unroll
    for (int it = 0; it < 4; ++it) {
        const int idx = it * 64 + lane;                 // float4 index in row
        const float4* wp = (const float4*)(W + (size_t)idx * 12);
        float4 wa = wp[0], wb = wp[1], wc = wp[2];
        w[it][0] = wa.x; w[it][1]  = wa.y; w[it][2]  = wa.z; w[it][3]  = wa.w;
        w[it][4] = wb.x; w[it][5]  = wb.y; w[it][6]  = wb.z; w[it][7]  = wb.w;
        w[it][8] = wc.x; w[it][9]  = wc.y; w[it][10] = wc.z; w[it][11] = wc.w;
    }

    const float bb = (lane < 3) ? bvec[lane] : 0.0f;

    for (int row = wave; row < rows; row += nwaves) {
        const float4* lrow = (const float4*)(latent + (size_t)row * D);
        float a0 = 0.0f, a1 = 0.0f, a2 = 0.0f;
        #pragma unroll
        for (int it = 0; it < 4; ++it) {
            float4 lv = lrow[it * 64 + lane];           // coalesced 1 KiB/instr
            // w layout per float4 of latent: [d0k0 d0k1 d0k2 d1k0 ... d3k2]
            a0 = fmaf(lv.x, w[it][0], a0);
            a1 = fmaf(lv.x, w[it][1], a1);
            a2 = fmaf(lv.x, w[it][2], a2);
            a0 = fmaf(lv.y, w[it][3], a0);
            a1 = fmaf(lv.y, w[it][4], a1);
            a2 = fmaf(lv.y, w[it][5], a2);
            a0 = fmaf(lv.z, w[it][6], a0);
            a1 = fmaf(lv.z, w[it][7], a1);
            a2 = fmaf(lv.z, w[it][8], a2);
            a0 = fmaf(lv.w, w[it][9],  a0);
            a1 = fmaf(lv.w, w[it][10], a1);
            a2 = fmaf(lv.w, w[it][11], a2);
        }
        // full-wave butterfly reduce (all lanes end with the row sums)
        #pragma unroll
        for (int m = 32; m >= 1; m >>= 1) {
            a0 += __shfl_xor(a0, m, 64);
            a1 += __shfl_xor(a1, m, 64);
            a2 += __shfl_xor(a2, m, 64);
        }
        if (lane < 3) {
            const float t  = (lane == 0) ? a0 : (lane == 1 ? a1 : a2);
            const float nz = noise[(size_t)row * 3 + lane];
            out[(size_t)row * 3 + lane] = fmaf(P, nz, Q * (t + bb));
        }
    }
}

extern "C" void kernel_launch(void* const* d_in, const int* in_sizes, int n_in,
                              void* d_out, int out_size, void* d_ws, size_t ws_size,
                              hipStream_t stream) {
    const float* latent = (const float*)d_in[0];
    const float* W      = (const float*)d_in[1];
    const float* bvec   = (const float*)d_in[2];
    const float* noise  = (const float*)d_in[3];
    const int*   steps  = (const int*)d_in[4];
    float* out = (float*)d_out;

    const int rows = in_sizes[0] / D;           // 4*8192 = 32768
    const int blocks = 2048;                    // 8 blocks/CU, grid-stride rows
    diff_init_kernel<<<blocks, 256, 0, stream>>>(latent, W, bvec, noise, steps,
                                                 out, rows);
}